// Round 14
// baseline (163.112 us; speedup 1.0000x reference)
//
#include <hip/hip_runtime.h>
#include <hip/hip_bf16.h>

// DynamicFilter fused, R14 = R13 + 16x32 tile / 512-thread blocks.
//
// R13 (101us main): no pipe saturated (VALU 54, MFMA 28, occ 40) -- fixed
// per-block costs (stage, barriers, epilogue) + 2.25x halo redundancy are
// the remaining fat. R14 doubles the tile along x: 4096 blocks x 512 thr,
// stage redundancy 1.87x (960 px / 512 out), conv1 45 M-tiles per block
// (vs 2x25 for same area), same 16 waves/CU (2 blocks x 8 waves, 65.3KB
// LDS). Wave-level work shape identical to R13 (verified): 6 M-tiles conv1,
// 4 N-tiles x 25 tap-major MFMAs conv2, 2 barriers. leaky = fmax(x, 0.1x).
//
// Layout (re-derived for 36-wide h grid):
//  * xs0[24][40] fp32 (epilogue img), pxc[24][40] packed bf16(img|ref).
//  * hs 720 px x 40sh (80B stride, 2-way alias = free) = 57.6KB.
//  * conv1 A direct-gather from pxc (8 dwords/lane per M-tile, masked pads);
//    B-frags from w1c[32ch][64k] (k=2*tap+ci, k>=50 zero).
//  * conv2 tap-major: K=32 chpos of one tap, B = base + compile-time imm
//    (dy*36+dx)*80; A streams from w2t[25][16][32chpos] (L1-hot).
//  * epilogue: f=kg*4+r2, shfl_down(16/32), lanes 0-15 store.
// d_ws: w1c @0 (4KB), w2t @4096 (25.6KB). prep kernel unchanged.

typedef __attribute__((ext_vector_type(8))) short bf16x8;
typedef __attribute__((ext_vector_type(4))) float f32x4;

#define HH 512
#define WW 512
#define TX 32                  // tile cols
#define TY 16                  // tile rows
#define XS_H 24
#define XS_W 40
#define HS_R 20
#define HS_C 36
#define NPX (HS_R * HS_C)      // 720
#define PXS 40                 // shorts per px in hs (80B stride)

__device__ __forceinline__ unsigned short f2bf(float x) {
    union { float f; unsigned int u; } v; v.f = x;
    unsigned int u = v.u;
    u += 0x7FFFu + ((u >> 16) & 1u);   // round-to-nearest-even
    return (unsigned short)(u >> 16);
}

__device__ __forceinline__ unsigned int pack_bf2(float a, float b) {
    __hip_bfloat162 h2 = __float22bfloat162_rn(make_float2(a, b));
    union { __hip_bfloat162 h; unsigned int u; } cv; cv.h = h2;
    return cv.u;
}

__device__ __forceinline__ bf16x8 dw4_to_frag(unsigned int d0, unsigned int d1,
                                              unsigned int d2, unsigned int d3) {
    union { unsigned int u[4]; bf16x8 f; } cv;
    cv.u[0] = d0; cv.u[1] = d1; cv.u[2] = d2; cv.u[3] = d3;
    return cv.f;
}

__global__ void dynfilt_prep(const float* __restrict__ w1,
                             const float* __restrict__ w2,
                             unsigned short* __restrict__ w1c,
                             unsigned short* __restrict__ w2t)
{
    int gid = blockIdx.x * 256 + threadIdx.x;   // 8192 threads
    // w1c[ch32][k64]: k = 2*tap + ci; k>=50 -> 0
    for (int i = gid; i < 32 * 64; i += 8192) {
        int ch = i >> 6, k = i & 63;
        int tap = k >> 1, ci = k & 1;
        w1c[i] = (k < 50) ? f2bf(w1[(ch * 2 + ci) * 25 + tap]) : (unsigned short)0;
    }
    // w2t[tap25][f16][chpos32]: chpos 2i -> ch i, 2i+1 -> ch 16+i; f>=9 zero
    for (int i = gid; i < 25 * 16 * 32; i += 8192) {
        int p = i & 31;
        int f = (i >> 5) & 15;
        int tap = i >> 9;   // 0..24
        int ch = (p & 1) * 16 + (p >> 1);
        w2t[i] = (f < 9) ? f2bf(w2[(f * 32 + ch) * 25 + tap]) : (unsigned short)0;
    }
}

__global__
__attribute__((amdgpu_flat_work_group_size(512, 512), amdgpu_waves_per_eu(4)))
void dynfilt_main(const float* __restrict__ image,
                  const float* __restrict__ refer,
                  const float* __restrict__ b1,
                  const float* __restrict__ b2,
                  const unsigned short* __restrict__ w1c,
                  const unsigned short* __restrict__ w2t,
                  float* __restrict__ out)
{
    __shared__ float xs0[XS_H][XS_W];           // image fp32 (epilogue)
    __shared__ unsigned int pxc[XS_H * XS_W];   // packed (bf16 img | bf16 ref)
    __shared__ __align__(16) unsigned short hs[NPX * PXS];

    const int t   = threadIdx.x;
    const int gx0 = blockIdx.x * TX;
    const int gy0 = blockIdx.y * TY;
    const int b   = blockIdx.z;

    // ---- stage halo: rows gy0-4..gy0+19 (24), cols gx0-4..gx0+35 (40) ----
    #pragma unroll 1
    for (int idx = t; idx < XS_H * XS_W; idx += 512) {
        int r = idx / XS_W, c = idx - (idx / XS_W) * XS_W;
        int gy = gy0 - 4 + r, gx = gx0 - 4 + c;
        float vi = 0.f, vr = 0.f;
        if ((unsigned)gy < HH && (unsigned)gx < WW) {
            size_t o = ((size_t)b * HH + gy) * WW + gx;
            vi = image[o];
            vr = refer[o];
        }
        xs0[r][c] = vi;
        pxc[idx]  = pack_bf2(vi, vr);
    }
    __syncthreads();   // xs0/pxc ready

    const int lane = t & 63;
    const int wv   = t >> 6;          // 0..7
    const int n    = lane & 15;
    const int kg   = lane >> 4;

    // ---- conv1 B-frags (w1c global, L1-hot) ----
    bf16x8 bfr[2][2];
    #pragma unroll
    for (int nt = 0; nt < 2; ++nt)
        #pragma unroll
        for (int s = 0; s < 2; ++s)
            bfr[nt][s] = *(const bf16x8*)(w1c + (nt * 16 + n) * 64 + s * 32 + kg * 8);

    // ---- per-lane pxc dword offsets for the 8 gathered taps ----
    int t0o[4], t1o[4];
    unsigned int t1m[4];
    #pragma unroll
    for (int j = 0; j < 4; ++j) {
        int tap0 = kg * 4 + j;                       // 0..15, always valid
        t0o[j] = (tap0 / 5) * XS_W + tap0 % 5;
        int tap1 = 16 + kg * 4 + j;                  // valid iff <= 24
        int vld  = (tap1 <= 24) ? 1 : 0;
        int tc   = vld ? tap1 : 0;
        t1o[j] = (tc / 5) * XS_W + tc % 5;
        t1m[j] = vld ? 0xFFFFFFFFu : 0u;
    }

    // px = mt*16 + n over 36-wide h grid; mt = m*8 + wv; px step = 128
    int px0 = wv * 16 + n;
    int pr = px0 / HS_C, pc = px0 - (px0 / HS_C) * HS_C;

    f32x4 d[6][2];
    #pragma unroll
    for (int m = 0; m < 6; ++m) {
        d[m][0] = (f32x4){0.f, 0.f, 0.f, 0.f};
        d[m][1] = (f32x4){0.f, 0.f, 0.f, 0.f};
    }

    // ---- conv1 GEMM: barrier-free direct gather from pxc (45 M-tiles) ----
    #pragma unroll
    for (int m = 0; m < 6; ++m) {
        int mt = m * 8 + wv;
        if (mt < 45) {   // wave-uniform guard
            const unsigned int* base = pxc + (pr * XS_W + pc);
            unsigned int a0d[4], a1d[4];
            #pragma unroll
            for (int j = 0; j < 4; ++j) a0d[j] = base[t0o[j]];
            #pragma unroll
            for (int j = 0; j < 4; ++j) a1d[j] = base[t1o[j]] & t1m[j];
            bf16x8 a0 = dw4_to_frag(a0d[0], a0d[1], a0d[2], a0d[3]);
            bf16x8 a1 = dw4_to_frag(a1d[0], a1d[1], a1d[2], a1d[3]);
            d[m][0] = __builtin_amdgcn_mfma_f32_16x16x32_bf16(a0, bfr[0][0], d[m][0], 0, 0, 0);
            d[m][0] = __builtin_amdgcn_mfma_f32_16x16x32_bf16(a1, bfr[0][1], d[m][0], 0, 0, 0);
            d[m][1] = __builtin_amdgcn_mfma_f32_16x16x32_bf16(a0, bfr[1][0], d[m][1], 0, 0, 0);
            d[m][1] = __builtin_amdgcn_mfma_f32_16x16x32_bf16(a1, bfr[1][1], d[m][1], 0, 0, 0);
        }
        // advance px by 128: 128 = 3*36 + 20 -> pr += 3, pc += 20, wrap once
        pc += 20; pr += 3;
        int w = (pc >= HS_C) ? 1 : 0;
        pc -= HS_C * w; pr += w;
    }

    // ---- h write-back: bias + leaky(max) + OOB-zero, pack (ch n, ch n+16) ----
    {
        float bb0 = b1[n], bb1 = b1[16 + n];
        #pragma unroll
        for (int m = 0; m < 6; ++m) {
            int mt = m * 8 + wv;
            if (mt < 45) {
                #pragma unroll
                for (int r = 0; r < 4; ++r) {
                    int px = mt * 16 + kg * 4 + r;   // D row = (lane>>4)*4 + reg
                    int prr = px / HS_C, pcc = px - prr * HS_C;
                    int gy = gy0 - 2 + prr, gx = gx0 - 2 + pcc;
                    bool inb = ((unsigned)gy < HH) & ((unsigned)gx < WW);
                    float h0 = d[m][0][r] + bb0;
                    float h1 = d[m][1][r] + bb1;
                    h0 = fmaxf(h0, 0.1f * h0);       // leaky, slope<1
                    h1 = fmaxf(h1, 0.1f * h1);
                    if (!inb) { h0 = 0.f; h1 = 0.f; }
                    *(unsigned int*)(hs + px * PXS + 2 * n) = pack_bf2(h0, h1);
                }
            }
        }
    }
    __syncthreads();   // hs ready (all waves)

    // ---- conv2: tap-major MFMA GEMM, K=32 chpos of one tap ----
    // N-tile id = wv*4+i: py = id>>1 (0..15), cx = (id&1)*16
    const char* bbrow[4];
    #pragma unroll
    for (int i = 0; i < 4; ++i) {
        int id = wv * 4 + i;
        int py = id >> 1, cx = (id & 1) * 16;
        bbrow[i] = (const char*)hs + (((py * HS_C) + cx + n) * PXS + kg * 8) * 2;
    }

    f32x4 acc[4];
    #pragma unroll
    for (int i = 0; i < 4; ++i) acc[i] = (f32x4){0.f, 0.f, 0.f, 0.f};

    #pragma unroll
    for (int tap = 0; tap < 25; ++tap) {
        bf16x8 afr = *(const bf16x8*)(w2t + (tap * 16 + n) * 32 + kg * 8);
        const int sofs = ((tap / 5) * HS_C + tap % 5) * (PXS * 2);   // compile-time
        #pragma unroll
        for (int i = 0; i < 4; ++i) {
            bf16x8 bfrag = *(const bf16x8*)(bbrow[i] + sofs);
            acc[i] = __builtin_amdgcn_mfma_f32_16x16x32_bf16(afr, bfrag, acc[i], 0, 0, 0);
        }
    }

    // ---- epilogue: out = sum_f (filt_f + b2_f) * image[y+fy-1][x+fx-1] ----
    float b2r[4];
    int fyr[4], fxr[4];
    #pragma unroll
    for (int r2 = 0; r2 < 4; ++r2) {
        int f = kg * 4 + r2;
        b2r[r2] = (f < 9) ? b2[f] : 0.f;
        int fy = f / 3;
        fyr[r2] = fy; fxr[r2] = f - fy * 3;
    }
    #pragma unroll
    for (int i = 0; i < 4; ++i) {
        int id = wv * 4 + i;
        int py = id >> 1, cx = (id & 1) * 16;
        float partial = 0.f;
        #pragma unroll
        for (int r2 = 0; r2 < 4; ++r2) {
            float img = xs0[py + fyr[r2] + 3][cx + n + fxr[r2] + 3];
            partial += (acc[i][r2] + b2r[r2]) * img;   // exact-zero term for f>=9
        }
        partial += __shfl_down(partial, 16, 64);
        partial += __shfl_down(partial, 32, 64);
        if (lane < 16)
            out[((size_t)b * HH + gy0 + py) * WW + gx0 + cx + n] = partial;
    }
}

extern "C" void kernel_launch(void* const* d_in, const int* in_sizes, int n_in,
                              void* d_out, int out_size, void* d_ws, size_t ws_size,
                              hipStream_t stream) {
    const float* image = (const float*)d_in[0];
    const float* refer = (const float*)d_in[1];
    const float* w1    = (const float*)d_in[2];
    const float* b1    = (const float*)d_in[3];
    const float* w2    = (const float*)d_in[4];
    const float* b2    = (const float*)d_in[5];

    unsigned short* w1c = (unsigned short*)d_ws;                   // 4 KB
    unsigned short* w2t = (unsigned short*)((char*)d_ws + 4096);   // 25.6 KB
    // ws re-poisoned before every launch -> prep must (and does) run every call

    hipLaunchKernelGGL(dynfilt_prep, dim3(32), dim3(256), 0, stream, w1, w2, w1c, w2t);

    dim3 grid(WW / TX, HH / TY, 8);
    hipLaunchKernelGGL(dynfilt_main, grid, dim3(512), 0, stream,
                       image, refer, b1, b2, w1c, w2t, (float*)d_out);
}

// Round 15
// 156.223 us; speedup vs baseline: 1.0441x; 1.0441x over previous
//
#include <hip/hip_runtime.h>
#include <hip/hip_bf16.h>

// DynamicFilter fused, R15 = R13 (revert R14's 16x32 tile) + interior-block
// fast path.
//
// R14 (16x32, 512thr) regressed 101->107us main: halo FETCH dropped as
// predicted but bank-conflict cycles rose 18%->25% of runtime. Reverted.
// R13 budget: MFMA issue ~28us (matches MfmaUtil 28%), VALUBusy 54%; the
// VALU excess over necessary work is bounds masks (4cmp+2cndmask x28/wave),
// 28 runtime /20 divisions (h write-back), and stage clamps -- all dead
// weight for the 88% of blocks ((30/32)^2) that touch no image boundary.
// R15 adds a wave-uniform interior branch: stage without bounds checks,
// h write-back without masks/divisions (address affine in m,r). Boundary
// blocks keep the R13-verbatim path.
//
// Structure (R13-verified): stage(xs0+pxc) -> conv1 MFMA GEMM with direct
// pxc gather (barrier-free, 8 dwords/lane/Mtile, masked pad taps) -> h
// write-back (leaky=fmax, OOB-zero, chpos-packed) -> conv2 tap-major GEMM
// (K=32 chpos of one tap, imm tap offsets, w2t L1-hot) -> epilogue
// shfl_down(16/32) reduce, lanes 0-15 store.
// LDS: xs0 2.3K + pxc 2.3K + hs 32K = 36.6KB -> 4 blocks/CU.
// d_ws: w1c bf16 [32ch][64k] @0 (k>=50 zero), w2t bf16 [25tap][16f][32chpos]
// @4096 (f>=9 zero; chpos 2i->ch i, 2i+1->ch 16+i).

typedef __attribute__((ext_vector_type(8))) short bf16x8;
typedef __attribute__((ext_vector_type(4))) float f32x4;

#define HH 512
#define WW 512
#define TILE 16
#define XS_H 24
#define XS_W 24
#define HS_R 20
#define HS_C 20
#define PXS 40                 // shorts per px in hs (80B stride, 2-way alias)

__device__ __forceinline__ unsigned short f2bf(float x) {
    union { float f; unsigned int u; } v; v.f = x;
    unsigned int u = v.u;
    u += 0x7FFFu + ((u >> 16) & 1u);   // round-to-nearest-even
    return (unsigned short)(u >> 16);
}

__device__ __forceinline__ unsigned int pack_bf2(float a, float b) {
    __hip_bfloat162 h2 = __float22bfloat162_rn(make_float2(a, b));
    union { __hip_bfloat162 h; unsigned int u; } cv; cv.h = h2;
    return cv.u;
}

__device__ __forceinline__ bf16x8 dw4_to_frag(unsigned int d0, unsigned int d1,
                                              unsigned int d2, unsigned int d3) {
    union { unsigned int u[4]; bf16x8 f; } cv;
    cv.u[0] = d0; cv.u[1] = d1; cv.u[2] = d2; cv.u[3] = d3;
    return cv.f;
}

__global__ void dynfilt_prep(const float* __restrict__ w1,
                             const float* __restrict__ w2,
                             unsigned short* __restrict__ w1c,
                             unsigned short* __restrict__ w2t)
{
    int gid = blockIdx.x * 256 + threadIdx.x;   // 8192 threads
    // w1c[ch32][k64]: k = 2*tap + ci; k>=50 -> 0
    for (int i = gid; i < 32 * 64; i += 8192) {
        int ch = i >> 6, k = i & 63;
        int tap = k >> 1, ci = k & 1;
        w1c[i] = (k < 50) ? f2bf(w1[(ch * 2 + ci) * 25 + tap]) : (unsigned short)0;
    }
    // w2t[tap25][f16][chpos32]: chpos 2i -> ch i, 2i+1 -> ch 16+i; f>=9 zero
    for (int i = gid; i < 25 * 16 * 32; i += 8192) {
        int p = i & 31;
        int f = (i >> 5) & 15;
        int tap = i >> 9;   // 0..24
        int ch = (p & 1) * 16 + (p >> 1);
        w2t[i] = (f < 9) ? f2bf(w2[(f * 32 + ch) * 25 + tap]) : (unsigned short)0;
    }
}

__global__
__attribute__((amdgpu_flat_work_group_size(256, 256), amdgpu_waves_per_eu(4)))
void dynfilt_main(const float* __restrict__ image,
                  const float* __restrict__ refer,
                  const float* __restrict__ b1,
                  const float* __restrict__ b2,
                  const unsigned short* __restrict__ w1c,
                  const unsigned short* __restrict__ w2t,
                  float* __restrict__ out)
{
    __shared__ float xs0[XS_H][XS_W];           // image fp32 (epilogue)
    __shared__ unsigned int pxc[XS_H * XS_W];   // packed (bf16 img | bf16 ref)
    __shared__ __align__(16) unsigned short hs[HS_R * HS_C * PXS];

    const int t   = threadIdx.x;
    const int gx0 = blockIdx.x * TILE;
    const int gy0 = blockIdx.y * TILE;
    const int b   = blockIdx.z;

    // whole halo (rows gy0-4..+19, cols gx0-4..+19) in-bounds?
    const bool interior = (gy0 >= 4) && (gy0 + XS_H - 4 <= HH) &&
                          (gx0 >= 4) && (gx0 + XS_W - 4 <= WW);

    // ---- stage halo: xs0 (image fp32) + pxc (packed img/ref bf16) ----
    if (interior) {
        const float* ib = image + ((size_t)b * HH + gy0 - 4) * WW + gx0 - 4;
        const float* rb = refer + ((size_t)b * HH + gy0 - 4) * WW + gx0 - 4;
        #pragma unroll 1
        for (int idx = t; idx < XS_H * XS_W; idx += 256) {
            int r = idx / XS_W, c = idx - (idx / XS_W) * XS_W;
            float vi = ib[r * WW + c];
            float vr = rb[r * WW + c];
            xs0[r][c] = vi;
            pxc[idx]  = pack_bf2(vi, vr);
        }
    } else {
        #pragma unroll 1
        for (int idx = t; idx < XS_H * XS_W; idx += 256) {
            int r = idx / XS_W, c = idx - (idx / XS_W) * XS_W;
            int gy = gy0 - 4 + r, gx = gx0 - 4 + c;
            float vi = 0.f, vr = 0.f;
            if ((unsigned)gy < HH && (unsigned)gx < WW) {
                size_t o = ((size_t)b * HH + gy) * WW + gx;
                vi = image[o];
                vr = refer[o];
            }
            xs0[r][c] = vi;
            pxc[idx]  = pack_bf2(vi, vr);
        }
    }
    __syncthreads();   // xs0/pxc ready

    const int lane = t & 63;
    const int wv   = t >> 6;
    const int n    = lane & 15;
    const int kg   = lane >> 4;

    // ---- conv1 B-frags (w1c global, L1-hot) ----
    bf16x8 bfr[2][2];
    #pragma unroll
    for (int nt = 0; nt < 2; ++nt)
        #pragma unroll
        for (int s = 0; s < 2; ++s)
            bfr[nt][s] = *(const bf16x8*)(w1c + (nt * 16 + n) * 64 + s * 32 + kg * 8);

    // ---- per-lane pxc dword offsets for the 8 gathered taps ----
    int t0o[4], t1o[4];
    unsigned int t1m[4];
    #pragma unroll
    for (int j = 0; j < 4; ++j) {
        int tap0 = kg * 4 + j;                       // 0..15, always valid
        t0o[j] = (tap0 / 5) * XS_W + tap0 % 5;
        int tap1 = 16 + kg * 4 + j;                  // valid iff <= 24
        int vld  = (tap1 <= 24) ? 1 : 0;
        int tc   = vld ? tap1 : 0;
        t1o[j] = (tc / 5) * XS_W + tc % 5;
        t1m[j] = vld ? 0xFFFFFFFFu : 0u;
    }

    // px = mt*16 + n, raster (pr,pc) over 20-wide h grid; step px += 64
    int px0 = wv * 16 + n;
    int pr = px0 / 20, pc = px0 - (px0 / 20) * 20;

    f32x4 d[7][2];
    #pragma unroll
    for (int m = 0; m < 7; ++m) {
        d[m][0] = (f32x4){0.f, 0.f, 0.f, 0.f};
        d[m][1] = (f32x4){0.f, 0.f, 0.f, 0.f};
    }

    // ---- conv1 GEMM: barrier-free direct gather from pxc ----
    #pragma unroll
    for (int m = 0; m < 7; ++m) {
        int mt = m * 4 + wv;
        if (mt < 25) {   // wave-uniform guard
            const unsigned int* base = pxc + (pr * XS_W + pc);
            unsigned int a0d[4], a1d[4];
            #pragma unroll
            for (int j = 0; j < 4; ++j) a0d[j] = base[t0o[j]];
            #pragma unroll
            for (int j = 0; j < 4; ++j) a1d[j] = base[t1o[j]] & t1m[j];
            bf16x8 a0 = dw4_to_frag(a0d[0], a0d[1], a0d[2], a0d[3]);
            bf16x8 a1 = dw4_to_frag(a1d[0], a1d[1], a1d[2], a1d[3]);
            d[m][0] = __builtin_amdgcn_mfma_f32_16x16x32_bf16(a0, bfr[0][0], d[m][0], 0, 0, 0);
            d[m][0] = __builtin_amdgcn_mfma_f32_16x16x32_bf16(a1, bfr[0][1], d[m][0], 0, 0, 0);
            d[m][1] = __builtin_amdgcn_mfma_f32_16x16x32_bf16(a0, bfr[1][0], d[m][1], 0, 0, 0);
            d[m][1] = __builtin_amdgcn_mfma_f32_16x16x32_bf16(a1, bfr[1][1], d[m][1], 0, 0, 0);
        }
        // advance px by 64: pc += 4 (mod 20), pr += 3 (+1 on wrap)
        pc += 4; pr += 3;
        int w = (pc >= 20) ? 1 : 0;
        pc -= 20 * w; pr += w;
    }

    // ---- h write-back: bias + leaky + pack (ch n, ch n+16) ----
    {
        float bb0 = b1[n], bb1 = b1[16 + n];
        if (interior) {
            // no masks, no divisions: hs addr affine in (m,r)
            unsigned short* hp = hs + (wv * 16 + kg * 4) * PXS + 2 * n;
            #pragma unroll
            for (int m = 0; m < 7; ++m) {
                int mt = m * 4 + wv;
                if (mt < 25) {
                    #pragma unroll
                    for (int r = 0; r < 4; ++r) {
                        float h0 = d[m][0][r] + bb0;
                        float h1 = d[m][1][r] + bb1;
                        h0 = fmaxf(h0, 0.1f * h0);
                        h1 = fmaxf(h1, 0.1f * h1);
                        *(unsigned int*)(hp + (m * 64 + r) * PXS) = pack_bf2(h0, h1);
                    }
                }
            }
        } else {
            #pragma unroll
            for (int m = 0; m < 7; ++m) {
                int mt = m * 4 + wv;
                if (mt < 25) {
                    #pragma unroll
                    for (int r = 0; r < 4; ++r) {
                        int px = mt * 16 + kg * 4 + r;   // D row = (lane>>4)*4 + reg
                        int prr = px / HS_C, pcc = px - prr * HS_C;
                        int gy = gy0 - 2 + prr, gx = gx0 - 2 + pcc;
                        bool inb = ((unsigned)gy < HH) & ((unsigned)gx < WW);
                        float h0 = d[m][0][r] + bb0;
                        float h1 = d[m][1][r] + bb1;
                        h0 = fmaxf(h0, 0.1f * h0);
                        h1 = fmaxf(h1, 0.1f * h1);
                        if (!inb) { h0 = 0.f; h1 = 0.f; }
                        *(unsigned int*)(hs + px * PXS + 2 * n) = pack_bf2(h0, h1);
                    }
                }
            }
        }
    }
    __syncthreads();   // hs ready (all waves)

    // ---- conv2: tap-major MFMA GEMM, K=32 chpos of one tap ----
    const char* bbrow[4];
    #pragma unroll
    for (int i = 0; i < 4; ++i)
        bbrow[i] = (const char*)hs + (((wv * 4 + i) * HS_C + n) * PXS + kg * 8) * 2;

    f32x4 acc[4];
    #pragma unroll
    for (int i = 0; i < 4; ++i) acc[i] = (f32x4){0.f, 0.f, 0.f, 0.f};

    #pragma unroll
    for (int tap = 0; tap < 25; ++tap) {
        bf16x8 afr = *(const bf16x8*)(w2t + (tap * 16 + n) * 32 + kg * 8);
        const int sofs = ((tap / 5) * HS_C + tap % 5) * (PXS * 2);   // compile-time
        #pragma unroll
        for (int i = 0; i < 4; ++i) {
            bf16x8 bfrag = *(const bf16x8*)(bbrow[i] + sofs);
            acc[i] = __builtin_amdgcn_mfma_f32_16x16x32_bf16(afr, bfrag, acc[i], 0, 0, 0);
        }
    }

    // ---- epilogue: out = sum_f (filt_f + b2_f) * image[y+fy-1][x+fx-1] ----
    float b2r[4];
    int fyr[4], fxr[4];
    #pragma unroll
    for (int r2 = 0; r2 < 4; ++r2) {
        int f = kg * 4 + r2;
        b2r[r2] = (f < 9) ? b2[f] : 0.f;
        int fy = f / 3;
        fyr[r2] = fy; fxr[r2] = f - fy * 3;
    }
    #pragma unroll
    for (int i = 0; i < 4; ++i) {
        int py = wv * 4 + i;
        float partial = 0.f;
        #pragma unroll
        for (int r2 = 0; r2 < 4; ++r2) {
            float img = xs0[py + fyr[r2] + 3][n + fxr[r2] + 3];
            partial += (acc[i][r2] + b2r[r2]) * img;   // exact-zero term for f>=9
        }
        partial += __shfl_down(partial, 16, 64);
        partial += __shfl_down(partial, 32, 64);
        if (lane < 16)
            out[((size_t)b * HH + gy0 + py) * WW + gx0 + n] = partial;
    }
}

extern "C" void kernel_launch(void* const* d_in, const int* in_sizes, int n_in,
                              void* d_out, int out_size, void* d_ws, size_t ws_size,
                              hipStream_t stream) {
    const float* image = (const float*)d_in[0];
    const float* refer = (const float*)d_in[1];
    const float* w1    = (const float*)d_in[2];
    const float* b1    = (const float*)d_in[3];
    const float* w2    = (const float*)d_in[4];
    const float* b2    = (const float*)d_in[5];

    unsigned short* w1c = (unsigned short*)d_ws;                   // 4 KB
    unsigned short* w2t = (unsigned short*)((char*)d_ws + 4096);   // 25.6 KB
    // ws re-poisoned before every launch -> prep must (and does) run every call

    hipLaunchKernelGGL(dynfilt_prep, dim3(32), dim3(256), 0, stream, w1, w2, w1c, w2t);

    dim3 grid(WW / TILE, HH / TILE, 8);
    hipLaunchKernelGGL(dynfilt_main, grid, dim3(256), 0, stream,
                       image, refer, b1, b2, w1c, w2t, (float*)d_out);
}